// Round 3
// baseline (201.226 us; speedup 1.0000x reference)
//
#include <hip/hip_runtime.h>
#include <hip/hip_fp16.h>
#include <math.h>

typedef _Float16 half8 __attribute__((ext_vector_type(8)));
typedef float floatx4 __attribute__((ext_vector_type(4)));

#define BB 32
#define SS 48
#define LL 64
#define FF 256

// ---- prep: swizzle W1 (256x256 fp32) into fp16 hi/lo MFMA-B fragment order ----
// layout: flat = ((kt*16 + nt)*64 + lane)*8 + j
//   element = W1[kt*32 + (lane>>4)*8 + j][nt*16 + (lane&15)]
__global__ __launch_bounds__(256) void prep_w(const float* __restrict__ W1,
                                              _Float16* __restrict__ whi,
                                              _Float16* __restrict__ wlo) {
    int idx = blockIdx.x * 256 + threadIdx.x;
    int j    = idx & 7;
    int lane = (idx >> 3) & 63;
    int nt   = (idx >> 9) & 15;
    int kt   = idx >> 13;
    int k = kt * 32 + ((lane >> 4) & 3) * 8 + j;
    int n = nt * 16 + (lane & 15);
    float x = W1[k * FF + n];
    _Float16 hi = (_Float16)x;
    _Float16 lo = (_Float16)(x - (float)hi);
    whi[idx] = hi;
    wlo[idx] = lo;
}

// ---- main fused kernel: one block per (b,s); no LDS for A, no K-loop barriers ----
__global__ __launch_bounds__(256, 3) void ida_mfma(
    const float* __restrict__ features,
    const float* __restrict__ src_locs,
    const float* __restrict__ tar_locs,
    const _Float16* __restrict__ whi,
    const _Float16* __restrict__ wlo,
    const float* __restrict__ b1,
    const float* __restrict__ W2,
    const float* __restrict__ b2,
    float* __restrict__ out)
{
    __shared__ float SP[LL * 4];    // layer-2 partials [row][wave]
    __shared__ float wbuf[LL];      // softmax weights
    __shared__ float red[4 * FF];   // weighted-sum cross-wave reduce

    const int t    = threadIdx.x;
    const int w    = t >> 6;        // wave id 0..3 -> owns cols 64w..64w+63
    const int lane = t & 63;
    const int quad = lane >> 4;
    const int l16  = lane & 15;
    const int bs   = blockIdx.x;
    const int b    = bs / SS;

    const float* Xg = features + (size_t)bs * (LL * FF);

    floatx4 acc[4][4] = {};         // [mt][nt_local]

    #pragma unroll
    for (int kt = 0; kt < 8; ++kt) {
        // B fragments for this wave's 4 N-tiles (L2-hot, shared by all blocks)
        half8 bhi[4], blo[4];
        #pragma unroll
        for (int nt = 0; nt < 4; ++nt) {
            size_t off = ((size_t)(kt * 16 + (w * 4 + nt)) * 64 + lane) * 8;
            bhi[nt] = *((const half8*)(whi + off));
            blo[nt] = *((const half8*)(wlo + off));
        }
        #pragma unroll
        for (int mt = 0; mt < 4; ++mt) {
            // A fragment for row-tile mt, straight from global (L2-shared across waves)
            const float4* p = (const float4*)(Xg + (mt * 16 + l16) * FF + kt * 32 + quad * 8);
            float4 x0 = p[0], x1 = p[1];
            float xs[8] = {x0.x, x0.y, x0.z, x0.w, x1.x, x1.y, x1.z, x1.w};
            half8 ahi, alo;
            #pragma unroll
            for (int j = 0; j < 8; ++j) {
                _Float16 h = (_Float16)xs[j];
                ahi[j] = h;
                alo[j] = (_Float16)(xs[j] - (float)h);
            }
            #pragma unroll
            for (int nt = 0; nt < 4; ++nt) {
                acc[mt][nt] = __builtin_amdgcn_mfma_f32_16x16x32_f16(ahi, bhi[nt], acc[mt][nt], 0, 0, 0);
                acc[mt][nt] = __builtin_amdgcn_mfma_f32_16x16x32_f16(ahi, blo[nt], acc[mt][nt], 0, 0, 0);
                acc[mt][nt] = __builtin_amdgcn_mfma_f32_16x16x32_f16(alo, bhi[nt], acc[mt][nt], 0, 0, 0);
            }
        }
    }

    // ---- layer-2: partial[row] = sum_n relu(H + b1) * W2, per wave over its 64 cols ----
    float b1v[4], w2v[4];
    #pragma unroll
    for (int nt = 0; nt < 4; ++nt) {
        int n = (w * 4 + nt) * 16 + l16;
        b1v[nt] = b1[n];
        w2v[nt] = W2[n];
    }
    #pragma unroll
    for (int mt = 0; mt < 4; ++mt) {
        #pragma unroll
        for (int r = 0; r < 4; ++r) {
            float p = 0.f;
            #pragma unroll
            for (int nt = 0; nt < 4; ++nt) {
                float h = fmaxf(acc[mt][nt][r] + b1v[nt], 0.f);
                p = fmaf(h, w2v[nt], p);
            }
            p += __shfl_xor(p, 1);
            p += __shfl_xor(p, 2);
            p += __shfl_xor(p, 4);
            p += __shfl_xor(p, 8);
            if (l16 == 0) SP[(mt * 16 + quad * 4 + r) * 4 + w] = p;
        }
    }
    __syncthreads();

    // ---- inverse-distance softmax over L=64 (wave 0) ----
    if (t < LL) {
        float s = SP[4 * t] + SP[4 * t + 1] + SP[4 * t + 2] + SP[4 * t + 3] + b2[0];
        float score = fmaxf(s, 0.f);
        float dx = src_locs[(b * LL + t) * 2 + 0] - tar_locs[b * 2 + 0];
        float dy = src_locs[(b * LL + t) * 2 + 1] - tar_locs[b * 2 + 1];
        float inv = 1.0f / sqrtf(dx * dx + dy * dy);
        float logit = score * inv;
        float m = logit;
        #pragma unroll
        for (int o = 32; o > 0; o >>= 1) m = fmaxf(m, __shfl_xor(m, o));
        float e = __expf(logit - m);
        float se = e;
        #pragma unroll
        for (int o = 32; o > 0; o >>= 1) se += __shfl_xor(se, o);
        wbuf[t] = e / se;
    }
    __syncthreads();

    // ---- weighted sum over stations (vectorized, rows split over waves) ----
    {
        const float4* Xg4 = (const float4*)Xg;
        floatx4 o = {0.f, 0.f, 0.f, 0.f};
        #pragma unroll
        for (int lr = 0; lr < 16; ++lr) {
            int l = w * 16 + lr;
            float wl = wbuf[l];
            float4 x = Xg4[l * 64 + lane];           // coalesced full row per wave
            o[0] = fmaf(x.x, wl, o[0]);
            o[1] = fmaf(x.y, wl, o[1]);
            o[2] = fmaf(x.z, wl, o[2]);
            o[3] = fmaf(x.w, wl, o[3]);
        }
        #pragma unroll
        for (int j = 0; j < 4; ++j)
            red[w * FF + lane * 4 + j] = o[j];
    }
    __syncthreads();
    {
        float o = red[0 * FF + t] + red[1 * FF + t] + red[2 * FF + t] + red[3 * FF + t];
        out[bs * FF + t] = o;
    }
}

extern "C" void kernel_launch(void* const* d_in, const int* in_sizes, int n_in,
                              void* d_out, int out_size, void* d_ws, size_t ws_size,
                              hipStream_t stream) {
    const float* features = (const float*)d_in[0];
    const float* src_locs = (const float*)d_in[1];
    const float* tar_locs = (const float*)d_in[2];
    const float* W1       = (const float*)d_in[3];
    const float* b1       = (const float*)d_in[4];
    const float* W2       = (const float*)d_in[5];
    const float* b2       = (const float*)d_in[6];
    float* out = (float*)d_out;

    _Float16* whi = (_Float16*)d_ws;               // 65536 fp16 = 128 KiB
    _Float16* wlo = whi + FF * FF;                 // 128 KiB more

    prep_w<<<dim3(FF * FF / 256), dim3(256), 0, stream>>>(W1, whi, wlo);
    ida_mfma<<<dim3(BB * SS), dim3(256), 0, stream>>>(
        features, src_locs, tar_locs, whi, wlo, b1, W2, b2, out);
}

// Round 5
// 182.616 us; speedup vs baseline: 1.1019x; 1.1019x over previous
//
#include <hip/hip_runtime.h>
#include <hip/hip_fp16.h>
#include <math.h>

typedef _Float16 half8 __attribute__((ext_vector_type(8)));
typedef float floatx4 __attribute__((ext_vector_type(4)));

#define BB 32
#define SS 48
#define LL 64
#define FF 256

// ---- prep: swizzle W1 (256x256 fp32) into fp16 hi/lo MFMA-B fragment order ----
// layout: flat = ((kt*16 + nt)*64 + lane)*8 + j
//   element = W1[kt*32 + (lane>>4)*8 + j][nt*16 + (lane&15)]
__global__ __launch_bounds__(256) void prep_w(const float* __restrict__ W1,
                                              _Float16* __restrict__ whi,
                                              _Float16* __restrict__ wlo) {
    int idx = blockIdx.x * 256 + threadIdx.x;
    int j    = idx & 7;
    int lane = (idx >> 3) & 63;
    int nt   = (idx >> 9) & 15;
    int kt   = idx >> 13;
    int k = kt * 32 + ((lane >> 4) & 3) * 8 + j;
    int n = nt * 16 + (lane & 15);
    float x = W1[k * FF + n];
    _Float16 hi = (_Float16)x;
    _Float16 lo = (_Float16)(x - (float)hi);
    whi[idx] = hi;
    wlo[idx] = lo;
}

// ---- main fused kernel: one block per (b,s) ----
// A staged half-K in LDS (R2-verified layout); B register-resident per K-half.
__global__ __launch_bounds__(256, 2) void ida_mfma(
    const float* __restrict__ features,
    const float* __restrict__ src_locs,
    const float* __restrict__ tar_locs,
    const _Float16* __restrict__ whi,
    const _Float16* __restrict__ wlo,
    const float* __restrict__ b1,
    const float* __restrict__ W2,
    const float* __restrict__ b2,
    float* __restrict__ out)
{
    __shared__ _Float16 Ahi[8192];   // 16 KiB: [slot = w*4+ktl][lane][8]
    __shared__ _Float16 Alo[8192];   // 16 KiB
    __shared__ float SP[LL * 4];     // layer-2 partials [row][wave]
    __shared__ float wbuf[LL];       // softmax weights
    __shared__ float red[4 * FF];    // weighted-sum cross-wave reduce

    const int t    = threadIdx.x;
    const int w    = t >> 6;         // wave id 0..3 -> owns cols 64w..64w+63
    const int lane = t & 63;
    const int quad = lane >> 4;
    const int l16  = lane & 15;
    const int bs   = blockIdx.x;
    const int b    = bs / SS;

    const float* Xg = features + (size_t)bs * (LL * FF);

    floatx4 acc[4][4] = {};          // [mt][nt_local]
    half8 bh[4][4], bl[4][4];        // B fragments for current K-half: [ktl][nt]

    // batch-load B for K-half 0 (32 x 16B loads, one latency wait)
    #pragma unroll
    for (int ktl = 0; ktl < 4; ++ktl)
        #pragma unroll
        for (int nt = 0; nt < 4; ++nt) {
            size_t off = ((size_t)(ktl * 16 + w * 4 + nt) * 64 + lane) * 8;
            bh[ktl][nt] = *((const half8*)(whi + off));
            bl[ktl][nt] = *((const half8*)(wlo + off));
        }

    for (int kh = 0; kh < 2; ++kh) {
        __syncthreads();             // previous half's A reads complete
        // stage+convert: wave w stages rows 16w..16w+15 for 4 ktl
        for (int ktl = 0; ktl < 4; ++ktl) {
            int kt = kh * 4 + ktl;
            const float4* p = (const float4*)(Xg + (w * 16 + l16) * FF + kt * 32 + quad * 8);
            float4 x0 = p[0], x1 = p[1];
            float xs[8] = {x0.x, x0.y, x0.z, x0.w, x1.x, x1.y, x1.z, x1.w};
            half8 hi, lo;
            #pragma unroll
            for (int j = 0; j < 8; ++j) {
                _Float16 h = (_Float16)xs[j];
                hi[j] = h;
                lo[j] = (_Float16)(xs[j] - (float)h);
            }
            *((half8*)&Ahi[((w * 4 + ktl) * 64 + lane) * 8]) = hi;
            *((half8*)&Alo[((w * 4 + ktl) * 64 + lane) * 8]) = lo;
        }
        __syncthreads();

        // compute this K-half: all B already in registers
        #pragma unroll
        for (int ktl = 0; ktl < 4; ++ktl) {
            #pragma unroll
            for (int mt = 0; mt < 4; ++mt) {
                half8 ahi = *((half8*)&Ahi[((mt * 4 + ktl) * 64 + lane) * 8]);
                half8 alo = *((half8*)&Alo[((mt * 4 + ktl) * 64 + lane) * 8]);
                #pragma unroll
                for (int nt = 0; nt < 4; ++nt) {
                    acc[mt][nt] = __builtin_amdgcn_mfma_f32_16x16x32_f16(ahi, bh[ktl][nt], acc[mt][nt], 0, 0, 0);
                    acc[mt][nt] = __builtin_amdgcn_mfma_f32_16x16x32_f16(ahi, bl[ktl][nt], acc[mt][nt], 0, 0, 0);
                    acc[mt][nt] = __builtin_amdgcn_mfma_f32_16x16x32_f16(alo, bh[ktl][nt], acc[mt][nt], 0, 0, 0);
                }
            }
        }

        // refill B registers for K-half 1; latency hides under next stage phase
        if (kh == 0) {
            #pragma unroll
            for (int ktl = 0; ktl < 4; ++ktl)
                #pragma unroll
                for (int nt = 0; nt < 4; ++nt) {
                    size_t off = ((size_t)((4 + ktl) * 16 + w * 4 + nt) * 64 + lane) * 8;
                    bh[ktl][nt] = *((const half8*)(whi + off));
                    bl[ktl][nt] = *((const half8*)(wlo + off));
                }
        }
    }

    // ---- layer-2: partial[row] = sum_n relu(H + b1) * W2, per wave over its 64 cols ----
    float b1v[4], w2v[4];
    #pragma unroll
    for (int nt = 0; nt < 4; ++nt) {
        int n = (w * 4 + nt) * 16 + l16;
        b1v[nt] = b1[n];
        w2v[nt] = W2[n];
    }
    #pragma unroll
    for (int mt = 0; mt < 4; ++mt) {
        #pragma unroll
        for (int r = 0; r < 4; ++r) {
            float p = 0.f;
            #pragma unroll
            for (int nt = 0; nt < 4; ++nt) {
                float h = fmaxf(acc[mt][nt][r] + b1v[nt], 0.f);
                p = fmaf(h, w2v[nt], p);
            }
            p += __shfl_xor(p, 1);
            p += __shfl_xor(p, 2);
            p += __shfl_xor(p, 4);
            p += __shfl_xor(p, 8);
            if (l16 == 0) SP[(mt * 16 + quad * 4 + r) * 4 + w] = p;
        }
    }
    __syncthreads();

    // ---- inverse-distance softmax over L=64 (wave 0) ----
    if (t < LL) {
        float s = SP[4 * t] + SP[4 * t + 1] + SP[4 * t + 2] + SP[4 * t + 3] + b2[0];
        float score = fmaxf(s, 0.f);
        float dx = src_locs[(b * LL + t) * 2 + 0] - tar_locs[b * 2 + 0];
        float dy = src_locs[(b * LL + t) * 2 + 1] - tar_locs[b * 2 + 1];
        float inv = 1.0f / sqrtf(dx * dx + dy * dy);
        float logit = score * inv;
        float m = logit;
        #pragma unroll
        for (int o = 32; o > 0; o >>= 1) m = fmaxf(m, __shfl_xor(m, o));
        float e = __expf(logit - m);
        float se = e;
        #pragma unroll
        for (int o = 32; o > 0; o >>= 1) se += __shfl_xor(se, o);
        wbuf[t] = e / se;
    }
    __syncthreads();

    // ---- weighted sum over stations (vectorized, rows split over waves) ----
    {
        const float4* Xg4 = (const float4*)Xg;
        floatx4 o = {0.f, 0.f, 0.f, 0.f};
        #pragma unroll
        for (int lr = 0; lr < 16; ++lr) {
            int l = w * 16 + lr;
            float wl = wbuf[l];
            float4 x = Xg4[l * 64 + lane];
            o[0] = fmaf(x.x, wl, o[0]);
            o[1] = fmaf(x.y, wl, o[1]);
            o[2] = fmaf(x.z, wl, o[2]);
            o[3] = fmaf(x.w, wl, o[3]);
        }
        #pragma unroll
        for (int j = 0; j < 4; ++j)
            red[w * FF + lane * 4 + j] = o[j];
    }
    __syncthreads();
    {
        float o = red[0 * FF + t] + red[1 * FF + t] + red[2 * FF + t] + red[3 * FF + t];
        out[bs * FF + t] = o;
    }
}

extern "C" void kernel_launch(void* const* d_in, const int* in_sizes, int n_in,
                              void* d_out, int out_size, void* d_ws, size_t ws_size,
                              hipStream_t stream) {
    const float* features = (const float*)d_in[0];
    const float* src_locs = (const float*)d_in[1];
    const float* tar_locs = (const float*)d_in[2];
    const float* W1       = (const float*)d_in[3];
    const float* b1       = (const float*)d_in[4];
    const float* W2       = (const float*)d_in[5];
    const float* b2       = (const float*)d_in[6];
    float* out = (float*)d_out;

    _Float16* whi = (_Float16*)d_ws;               // 128 KiB
    _Float16* wlo = whi + FF * FF;                 // 128 KiB

    prep_w<<<dim3(FF * FF / 256), dim3(256), 0, stream>>>(W1, whi, wlo);
    ida_mfma<<<dim3(BB * SS), dim3(256), 0, stream>>>(
        features, src_locs, tar_locs, whi, wlo, b1, W2, b2, out);
}